// Round 1
// baseline (154.662 us; speedup 1.0000x reference)
//
#include <hip/hip_runtime.h>
#include <math.h>

// Problem dims (hardcoded per reference setup_inputs)
#define N_  8
#define C_  256
#define T_  30
#define H_  64
#define W_  44
#define S_  8      // NUM_STRIPES
#define SH_ 8      // H_/S_
#define TOPK_ 2

#define BLK_FLOATS (SH_*W_)       // 352 contiguous floats per (n,c,t,stripe)
#define BLK_F4     (BLK_FLOATS/4) // 88 float4
#define NFEATS     (N_*C_*T_*S_)  // 491520
#define NSCORES    (N_*T_*S_)     // 1920

// ---------------- Stage 1: feats[(n*C+c)*T+t)*S+s] = mean of 352-float block
__global__ __launch_bounds__(256) void feats_kernel(const float* __restrict__ x,
                                                    float* __restrict__ feats) {
    const int wave = (blockIdx.x * blockDim.x + threadIdx.x) >> 6;
    const int lane = threadIdx.x & 63;
    if (wave >= NFEATS) return;
    // feat id f: f>>3 = (n*C+c)*T+t ; f&7 = stripe s
    const float4* p = (const float4*)(x + (size_t)(wave >> 3) * (size_t)(H_*W_)
                                        + (size_t)(wave & 7) * BLK_FLOATS);
    float4 v = p[lane];
    float sum = v.x + v.y + v.z + v.w;
    if (lane < BLK_F4 - 64) {           // 88 float4: lanes 0..23 take a second one
        float4 u = p[lane + 64];
        sum += u.x + u.y + u.z + u.w;
    }
    #pragma unroll
    for (int o = 32; o > 0; o >>= 1) sum += __shfl_xor(sum, o, 64);
    if (lane == 0) feats[wave] = sum * (1.0f / BLK_FLOATS);
}

// ---------------- Stage 2: scores[(n*S+s)*T+t] = sqrt(max(sum_c feats^2, 1e-6))
__global__ __launch_bounds__(256) void scores_kernel(const float* __restrict__ feats,
                                                     float* __restrict__ scores) {
    const int wave = (blockIdx.x * blockDim.x + threadIdx.x) >> 6;
    const int lane = threadIdx.x & 63;
    if (wave >= NSCORES) return;
    const int s = wave & (S_ - 1);
    const int t = (wave >> 3) % T_;
    const int n = wave / (T_ * S_);
    float sum = 0.f;
    #pragma unroll
    for (int j = 0; j < 4; ++j) {
        const int c = lane + 64 * j;
        const float f = feats[((size_t)(n * C_ + c) * T_ + t) * S_ + s];
        sum += f * f;
    }
    #pragma unroll
    for (int o = 32; o > 0; o >>= 1) sum += __shfl_xor(sum, o, 64);
    if (lane == 0) scores[(n * S_ + s) * T_ + t] = sqrtf(fmaxf(sum, 1e-6f));
}

// ---------------- Stage 3: top-2 over t per (n,s); out[n][s*C+c] = mean of 2 frames
__global__ __launch_bounds__(256) void out_kernel(const float* __restrict__ feats,
                                                  const float* __restrict__ scores,
                                                  float* __restrict__ out) {
    const int b = blockIdx.x;     // 0..63 = n*S+s
    const int n = b >> 3, s = b & 7;
    const float* sc = scores + b * T_;
    // stable argmax (first occurrence wins ties) — matches jax.lax.top_k
    int i0 = 0; float v0 = sc[0];
    for (int t = 1; t < T_; ++t) { float v = sc[t]; if (v > v0) { v0 = v; i0 = t; } }
    int i1 = (i0 == 0) ? 1 : 0; float v1 = sc[i1];
    for (int t = 0; t < T_; ++t) {
        if (t == i0) continue;
        float v = sc[t]; if (v > v1) { v1 = v; i1 = t; }
    }
    const int c = threadIdx.x;    // 256 threads, one per channel
    const size_t base = (size_t)(n * C_ + c) * T_;
    const float a = feats[(base + i0) * S_ + s];
    const float bb = feats[(base + i1) * S_ + s];
    out[n * (S_ * C_) + s * C_ + c] = 0.5f * (a + bb);
}

extern "C" void kernel_launch(void* const* d_in, const int* in_sizes, int n_in,
                              void* d_out, int out_size, void* d_ws, size_t ws_size,
                              hipStream_t stream) {
    const float* x = (const float*)d_in[0];
    float* out = (float*)d_out;
    float* feats = (float*)d_ws;              // NFEATS floats (~1.97 MB)
    float* scores = feats + NFEATS;           // NSCORES floats

    // Stage 1: one wave per feat; 4 waves per 256-thread block
    feats_kernel<<<NFEATS / 4, 256, 0, stream>>>(x, feats);
    // Stage 2: one wave per score
    scores_kernel<<<(NSCORES + 3) / 4, 256, 0, stream>>>(feats, scores);
    // Stage 3: one block per (n, stripe)
    out_kernel<<<N_ * S_, 256, 0, stream>>>(feats, scores, out);
}

// Round 2
// 132.064 us; speedup vs baseline: 1.1711x; 1.1711x over previous
//
#include <hip/hip_runtime.h>
#include <math.h>

// Problem dims (hardcoded per reference setup_inputs)
#define N_  8
#define C_  256
#define T_  30
#define H_  64
#define W_  44
#define S_  8      // NUM_STRIPES
#define SH_ 8      // H_/S_

#define ROWS      (N_*C_*T_)      // 61440 rows of H*W = 2816 floats
#define NFEATS    (ROWS*S_)       // 491520
#define ROW_F4    (H_*W_/4)       // 704 float4 per row
#define STRIPE_F4 (SH_*W_/4)      // 88 float4 per stripe

// ---------------- Stage 1: one wave per (n,c,t) row -> 8 stripe means.
// 8 lanes per stripe: lane (8j+r) reads float4 indices 88j + r + 8i, i=0..10.
// Each load instruction = 8 aligned 128B segments = 16 full 64B lines, 0 waste.
__global__ __launch_bounds__(256) void feats_kernel(const float* __restrict__ x,
                                                    float* __restrict__ feats) {
    const int row  = (blockIdx.x * blockDim.x + threadIdx.x) >> 6;
    const int lane = threadIdx.x & 63;
    if (row >= ROWS) return;
    const int j = lane >> 3;        // stripe 0..7
    const int r = lane & 7;         // slot within stripe
    const float4* p = (const float4*)(x + (size_t)row * (H_*W_)) + STRIPE_F4 * j + r;
    float4 acc = make_float4(0.f, 0.f, 0.f, 0.f);
    #pragma unroll
    for (int i = 0; i < 11; ++i) {
        float4 v = p[8 * i];        // base + 128*i bytes: imm-offset loads
        acc.x += v.x; acc.y += v.y; acc.z += v.z; acc.w += v.w;
    }
    float sum = (acc.x + acc.y) + (acc.z + acc.w);
    sum += __shfl_xor(sum, 1, 64);
    sum += __shfl_xor(sum, 2, 64);
    sum += __shfl_xor(sum, 4, 64);
    if (r == 0) feats[row * S_ + j] = sum * (1.0f / (SH_ * W_));
}

// ---------------- Stage 2+3 fused: per (n,s) block: scores over t, top-2, output.
__global__ __launch_bounds__(256) void out_kernel(const float* __restrict__ feats,
                                                  float* __restrict__ out) {
    __shared__ float sc[32];
    const int b = blockIdx.x;          // 0..63 = n*S+s
    const int n = b >> 3, s = b & 7;
    const int tid = threadIdx.x, lane = tid & 63, w = tid >> 6;

    // scores[t] = sqrt(max(sum_c feats[n,c,t,s]^2, eps)); waves split the t's
    for (int t = w; t < T_; t += 4) {
        float sum = 0.f;
        #pragma unroll
        for (int jj = 0; jj < 4; ++jj) {
            const int c = lane + 64 * jj;
            const float f = feats[((size_t)(n * C_ + c) * T_ + t) * S_ + s];
            sum += f * f;
        }
        #pragma unroll
        for (int o = 32; o; o >>= 1) sum += __shfl_xor(sum, o, 64);
        if (lane == 0) sc[t] = sqrtf(fmaxf(sum, 1e-6f));
    }
    __syncthreads();

    // stable top-2 (first occurrence wins ties) — redundantly per thread, cheap
    int i0 = 0; float v0 = sc[0];
    for (int t = 1; t < T_; ++t) { float v = sc[t]; if (v > v0) { v0 = v; i0 = t; } }
    int i1 = (i0 == 0) ? 1 : 0; float v1 = sc[i1];
    for (int t = 0; t < T_; ++t) {
        if (t == i0) continue;
        float v = sc[t]; if (v > v1) { v1 = v; i1 = t; }
    }

    const int c = tid;                 // one thread per channel
    const size_t base = (size_t)(n * C_ + c) * T_;
    const float a  = feats[(base + i0) * S_ + s];
    const float bb = feats[(base + i1) * S_ + s];
    out[n * (S_ * C_) + s * C_ + c] = 0.5f * (a + bb);
}

extern "C" void kernel_launch(void* const* d_in, const int* in_sizes, int n_in,
                              void* d_out, int out_size, void* d_ws, size_t ws_size,
                              hipStream_t stream) {
    const float* x = (const float*)d_in[0];
    float* out = (float*)d_out;
    float* feats = (float*)d_ws;       // NFEATS floats (~1.97 MB)

    // Stage 1: one wave per row; 4 waves (4 rows) per 256-thread block
    feats_kernel<<<ROWS / 4, 256, 0, stream>>>(x, feats);
    // Stage 2+3: one block per (n, stripe)
    out_kernel<<<N_ * S_, 256, 0, stream>>>(feats, out);
}

// Round 4
// 118.773 us; speedup vs baseline: 1.3022x; 1.1119x over previous
//
#include <hip/hip_runtime.h>
#include <math.h>

// Problem dims (hardcoded per reference setup_inputs)
#define N_  8
#define C_  256
#define T_  30
#define H_  64
#define W_  44
#define S_  8      // NUM_STRIPES
#define SH_ 8      // H_/S_

#define ROWS      (N_*C_*T_)      // 61440 rows of H*W = 2816 floats
#define NFEATS    (ROWS*S_)       // 491520
#define STRIPE_F4 (SH_*W_/4)      // 88 float4 per stripe

#define ROWS_PER_WAVE 4
#define WAVES_ST1 (ROWS / ROWS_PER_WAVE)   // 15360 waves
#define BLOCKS_ST1 (WAVES_ST1 / 4)         // 3840 blocks of 256

// clang-native vector type: __builtin_nontemporal_load requires it
typedef float vf4 __attribute__((ext_vector_type(4)));

// ---------------- Stage 1: each wave -> 4 rows (2 adjacent rows x 2 iterations).
// Within a row: 8 lanes per stripe, lane (8j+r) reads float4 88j + r + 8i, i=0..10.
// Each load instruction = 8 aligned 128B segments = 16 full 64B lines, 0 waste.
// Nontemporal: x is read exactly once, don't pollute L1/L2.
__global__ __launch_bounds__(256) void feats_kernel(const float* __restrict__ x,
                                                    float* __restrict__ feats) {
    const int wid  = (blockIdx.x * blockDim.x + threadIdx.x) >> 6;
    const int lane = threadIdx.x & 63;
    const int j = lane >> 3;        // stripe 0..7
    const int r = lane & 7;         // slot within stripe
    const int off = STRIPE_F4 * j + r;

    #pragma unroll 1
    for (int it = 0; it < 2; ++it) {
        const int row0 = 2 * wid + it * (2 * WAVES_ST1);

        const vf4* p0 = (const vf4*)(x + (size_t)row0 * (H_*W_)) + off;
        const vf4* p1 = p0 + (H_*W_/4);   // row0 + 1 (adjacent)

        vf4 a0 = (vf4)(0.f);
        vf4 a1 = (vf4)(0.f);
        #pragma unroll
        for (int i = 0; i < 11; ++i) {
            vf4 v0 = __builtin_nontemporal_load(p0 + 8 * i);
            vf4 v1 = __builtin_nontemporal_load(p1 + 8 * i);
            a0 += v0;
            a1 += v1;
        }
        float s0 = (a0.x + a0.y) + (a0.z + a0.w);
        float s1 = (a1.x + a1.y) + (a1.z + a1.w);
        s0 += __shfl_xor(s0, 1, 64);
        s0 += __shfl_xor(s0, 2, 64);
        s0 += __shfl_xor(s0, 4, 64);
        s1 += __shfl_xor(s1, 1, 64);
        s1 += __shfl_xor(s1, 2, 64);
        s1 += __shfl_xor(s1, 4, 64);
        if (r == 0) {
            feats[(size_t)row0 * S_ + j]       = s0 * (1.0f / (SH_ * W_));
            feats[(size_t)(row0 + 1) * S_ + j] = s1 * (1.0f / (SH_ * W_));
        }
    }
}

// ---------------- Stage 2+3 fused: per (n,s) block: scores over t, top-2, output.
__global__ __launch_bounds__(256) void out_kernel(const float* __restrict__ feats,
                                                  float* __restrict__ out) {
    __shared__ float sc[32];
    const int b = blockIdx.x;          // 0..63 = n*S+s
    const int n = b >> 3, s = b & 7;
    const int tid = threadIdx.x, lane = tid & 63, w = tid >> 6;

    // scores[t] = sqrt(max(sum_c feats[n,c,t,s]^2, eps)); waves split the t's
    for (int t = w; t < T_; t += 4) {
        float sum = 0.f;
        #pragma unroll
        for (int jj = 0; jj < 4; ++jj) {
            const int c = lane + 64 * jj;
            const float f = feats[((size_t)(n * C_ + c) * T_ + t) * S_ + s];
            sum += f * f;
        }
        #pragma unroll
        for (int o = 32; o; o >>= 1) sum += __shfl_xor(sum, o, 64);
        if (lane == 0) sc[t] = sqrtf(fmaxf(sum, 1e-6f));
    }
    __syncthreads();

    // stable top-2 (first occurrence wins ties) — redundantly per thread, cheap
    int i0 = 0; float v0 = sc[0];
    for (int t = 1; t < T_; ++t) { float v = sc[t]; if (v > v0) { v0 = v; i0 = t; } }
    int i1 = (i0 == 0) ? 1 : 0; float v1 = sc[i1];
    for (int t = 0; t < T_; ++t) {
        if (t == i0) continue;
        float v = sc[t]; if (v > v1) { v1 = v; i1 = t; }
    }

    const int c = tid;                 // one thread per channel
    const size_t base = (size_t)(n * C_ + c) * T_;
    const float a  = feats[(base + i0) * S_ + s];
    const float bb = feats[(base + i1) * S_ + s];
    out[n * (S_ * C_) + s * C_ + c] = 0.5f * (a + bb);
}

extern "C" void kernel_launch(void* const* d_in, const int* in_sizes, int n_in,
                              void* d_out, int out_size, void* d_ws, size_t ws_size,
                              hipStream_t stream) {
    const float* x = (const float*)d_in[0];
    float* out = (float*)d_out;
    float* feats = (float*)d_ws;       // NFEATS floats (~1.97 MB)

    feats_kernel<<<BLOCKS_ST1, 256, 0, stream>>>(x, feats);
    out_kernel<<<N_ * S_, 256, 0, stream>>>(feats, out);
}